// Round 1
// baseline (652.950 us; speedup 1.0000x reference)
//
#include <hip/hip_runtime.h>
#include <hip/hip_bf16.h>

#define N_NODES 100000
#define N_EDGES 3200000
#define F_IN 512
#define F_OUT 256

typedef short bf16x8 __attribute__((ext_vector_type(8)));
typedef short bf16x4 __attribute__((ext_vector_type(4)));
typedef float f32x4 __attribute__((ext_vector_type(4)));

__device__ __forceinline__ short f2b(float f) {
    unsigned u = __builtin_bit_cast(unsigned, f);
    u += 0x7fffu + ((u >> 16) & 1u);   // round-to-nearest-even
    return (short)(u >> 16);
}
__device__ __forceinline__ float b2f(short s) {
    unsigned u = ((unsigned)(unsigned short)s) << 16;
    return __builtin_bit_cast(float, u);
}

// --- Kernel 0a: W [512][256] fp32 -> Wt [256][512] bf16 (transposed) ---
__global__ void k_wconv(const float* __restrict__ W, short* __restrict__ Wt) {
    int idx = blockIdx.x * 256 + threadIdx.x;   // 0..131071
    int k = idx >> 8;
    int n = idx & 255;
    Wt[n * F_IN + k] = f2b(W[idx]);
}

// --- Kernel 0b: row_ptr via lower_bound on sorted edge_row ---
__global__ void k_rowptr(const int* __restrict__ erow, int* __restrict__ rp) {
    int i = blockIdx.x * 256 + threadIdx.x;
    if (i > N_NODES) return;
    int lo = 0, hi = N_EDGES;
    while (lo < hi) {
        int mid = (lo + hi) >> 1;
        if (erow[mid] < i) lo = mid + 1; else hi = mid;
    }
    rp[i] = lo;
}

// --- Kernel 1: support_bf16 = x @ W  (bf16 MFMA, 128x128 tile) ---
// Block 256 threads = 4 waves in 2x2; each wave computes 64x64 = 4x4 tiles
// of 16x16 via mfma_f32_16x16x32_bf16, K-loop 512 in BK=32 steps.
__global__ __launch_bounds__(256) void k_gemm(const float* __restrict__ X,
                                              const short* __restrict__ Wt,
                                              short* __restrict__ S) {
    __shared__ short As[128 * 40];   // stride 40 bf16: b128-aligned rows, low conflicts
    const int tid  = threadIdx.x;
    const int wave = tid >> 6;
    const int lane = tid & 63;
    const int wr   = wave >> 1, wc = wave & 1;
    const int l15  = lane & 15, quad = lane >> 4;
    const int bm = blockIdx.x, bn = blockIdx.y;
    const long row_base = (long)bm * 128;

    f32x4 acc[4][4];
#pragma unroll
    for (int i = 0; i < 4; ++i)
#pragma unroll
        for (int j = 0; j < 4; ++j) acc[i][j] = (f32x4){0.f, 0.f, 0.f, 0.f};

    const int srow = tid >> 3;          // 0..31
    const int scol = (tid & 7) * 4;     // 0,4,..,28
    const short* wtb = Wt + (bn * 128 + wc * 64 + l15) * F_IN + quad * 8;
    const int afrag_base = (wr * 64 + l15) * 40 + quad * 8;

    for (int k0 = 0; k0 < F_IN; k0 += 32) {
        __syncthreads();
        // stage A tile [128][32] fp32 -> bf16 LDS
#pragma unroll
        for (int r = 0; r < 4; ++r) {
            int m = srow + r * 32;
            long gm = row_base + m;
            f32x4 v = (f32x4){0.f, 0.f, 0.f, 0.f};
            if (gm < N_NODES) v = *(const f32x4*)(X + gm * F_IN + k0 + scol);
            bf16x4 b = { f2b(v.x), f2b(v.y), f2b(v.z), f2b(v.w) };
            *(bf16x4*)&As[m * 40 + scol] = b;
        }
        __syncthreads();

        bf16x8 bfrag[4], afrag[4];
#pragma unroll
        for (int j = 0; j < 4; ++j)
            bfrag[j] = *(const bf16x8*)(wtb + j * 16 * F_IN + k0);
#pragma unroll
        for (int i = 0; i < 4; ++i)
            afrag[i] = *(const bf16x8*)&As[afrag_base + i * 16 * 40];
#pragma unroll
        for (int i = 0; i < 4; ++i)
#pragma unroll
            for (int j = 0; j < 4; ++j)
                acc[i][j] = __builtin_amdgcn_mfma_f32_16x16x32_bf16(
                    afrag[i], bfrag[j], acc[i][j], 0, 0, 0);
    }

    // epilogue: C/D layout col=lane&15, row=quad*4+reg
#pragma unroll
    for (int i = 0; i < 4; ++i) {
#pragma unroll
        for (int rg = 0; rg < 4; ++rg) {
            long gm = row_base + wr * 64 + i * 16 + quad * 4 + rg;
            if (gm < N_NODES) {
#pragma unroll
                for (int j = 0; j < 4; ++j) {
                    int gn = bn * 128 + wc * 64 + j * 16 + l15;
                    S[gm * F_OUT + gn] = f2b(acc[i][j][rg]);
                }
            }
        }
    }
}

// --- Kernel 2: out = spmm(adj, support). One wave per node, lane owns 4 cols.
__global__ __launch_bounds__(256) void k_spmm(const short* __restrict__ S,
                                              const int* __restrict__ ecol,
                                              const float* __restrict__ evalp,
                                              const int* __restrict__ rp,
                                              float* __restrict__ out) {
    const int wave = threadIdx.x >> 6, lane = threadIdx.x & 63;
    const int r = blockIdx.x * 4 + wave;            // grid = 25000 -> r < 100000
    const int lo = rp[r], hi = rp[r + 1];
    const short* sp = S + lane * 4;
    float a0 = 0.f, a1 = 0.f, a2 = 0.f, a3 = 0.f;
    if (lo < hi) {
        int c = ecol[lo];
        float v = evalp[lo];
        bf16x4 s = *(const bf16x4*)(sp + (long)c * F_OUT);
        for (int e = lo + 1; e < hi; ++e) {
            int c2 = ecol[e];                        // depth-2 pipeline:
            float v2 = evalp[e];                     // next gather issues while
            bf16x4 s2 = *(const bf16x4*)(sp + (long)c2 * F_OUT);  // current FMAs run
            a0 += v * b2f(s.x); a1 += v * b2f(s.y);
            a2 += v * b2f(s.z); a3 += v * b2f(s.w);
            v = v2; s = s2;
        }
        a0 += v * b2f(s.x); a1 += v * b2f(s.y);
        a2 += v * b2f(s.z); a3 += v * b2f(s.w);
    }
    f32x4 o = {a0, a1, a2, a3};
    *(f32x4*)(out + (long)r * F_OUT + lane * 4) = o;
}

extern "C" void kernel_launch(void* const* d_in, const int* in_sizes, int n_in,
                              void* d_out, int out_size, void* d_ws, size_t ws_size,
                              hipStream_t stream) {
    const float* x    = (const float*)d_in[0];
    const float* w    = (const float*)d_in[1];
    const int*   erow = (const int*)d_in[2];
    const int*   ecol = (const int*)d_in[3];
    const float* ev   = (const float*)d_in[4];
    float* out = (float*)d_out;

    // ws layout: [0,262144) Wt bf16 | [262144,662148) row_ptr | [1MiB, 1MiB+51.2MB) support bf16
    char* ws = (char*)d_ws;
    short* Wt = (short*)ws;
    int*   rp = (int*)(ws + 262144);
    short* S  = (short*)(ws + (1 << 20));

    k_wconv<<<512, 256, 0, stream>>>(w, Wt);
    k_rowptr<<<(N_NODES + 256) / 256, 256, 0, stream>>>(erow, rp);
    dim3 g((N_NODES + 127) / 128, F_OUT / 128);
    k_gemm<<<g, 256, 0, stream>>>(x, Wt, S);
    k_spmm<<<N_NODES / 4, 256, 0, stream>>>(S, ecol, ev, rp, out);
}

// Round 2
// 584.230 us; speedup vs baseline: 1.1176x; 1.1176x over previous
//
#include <hip/hip_runtime.h>

#define N_NODES 100000
#define N_EDGES 3200000
#define F_IN 512
#define F_OUT 256

typedef short bf16x8 __attribute__((ext_vector_type(8)));
typedef short bf16x4 __attribute__((ext_vector_type(4)));
typedef float f32x4 __attribute__((ext_vector_type(4)));
typedef unsigned u32x4 __attribute__((ext_vector_type(4)));

__device__ __forceinline__ short f2b(float f) {
    unsigned u = __builtin_bit_cast(unsigned, f);
    u += 0x7fffu + ((u >> 16) & 1u);   // round-to-nearest-even
    return (short)(u >> 16);
}
__device__ __forceinline__ float b2f(short s) {
    unsigned u = ((unsigned)(unsigned short)s) << 16;
    return __builtin_bit_cast(float, u);
}
// pack two fp32 -> two bf16 (round-half-up): 2 adds + 1 v_perm
__device__ __forceinline__ unsigned pack2(float f0, float f1) {
    unsigned u0 = __builtin_bit_cast(unsigned, f0) + 0x8000u;
    unsigned u1 = __builtin_bit_cast(unsigned, f1) + 0x8000u;
    return __builtin_amdgcn_perm(u1, u0, 0x07060302);  // [u0.hi16, u1.hi16]
}
__device__ __forceinline__ void load_lds16(const float* g, void* l) {
    __builtin_amdgcn_global_load_lds(
        (const __attribute__((address_space(1))) unsigned*)g,
        (__attribute__((address_space(3))) unsigned*)l, 16, 0, 0);
}

// --- Kernel 0a: W [512][256] fp32 -> Wt [256][512] bf16 (transposed) ---
__global__ void k_wconv(const float* __restrict__ W, short* __restrict__ Wt) {
    int idx = blockIdx.x * 256 + threadIdx.x;
    int k = idx >> 8;
    int n = idx & 255;
    Wt[n * F_IN + k] = f2b(W[idx]);
}

// --- Kernel 0b: row_ptr via lower_bound on sorted edge_row ---
__global__ void k_rowptr(const int* __restrict__ erow, int* __restrict__ rp) {
    int i = blockIdx.x * 256 + threadIdx.x;
    if (i > N_NODES) return;
    int lo = 0, hi = N_EDGES;
    while (lo < hi) {
        int mid = (lo + hi) >> 1;
        if (erow[mid] < i) lo = mid + 1; else hi = mid;
    }
    rp[i] = lo;
}

// --- Kernel 1: S = x @ W (bf16 MFMA). Block tile 128x256, 8 waves 2x4,
// wave tile 64x64. A staged fp32 via global_load_lds(16B); cvt in frag read.
__global__ __launch_bounds__(512, 4) void k_gemm(const float* __restrict__ X,
                                                 const short* __restrict__ Wt,
                                                 short* __restrict__ S) {
    __shared__ float As[128 * 32];   // 16 KB, row-major, row stride 128 B
    const int tid  = threadIdx.x;
    const int wave = tid >> 6;
    const int lane = tid & 63;
    const int wr   = wave >> 2;       // 0..1  row group (64 rows)
    const int wc   = wave & 3;        // 0..3  col group (64 cols)
    const int l15  = lane & 15, quad = lane >> 4;
    const long row_base = (long)blockIdx.x * 128;

    f32x4 acc[4][4];
#pragma unroll
    for (int i = 0; i < 4; ++i)
#pragma unroll
        for (int j = 0; j < 4; ++j) acc[i][j] = (f32x4){0.f, 0.f, 0.f, 0.f};

    // staging: thread t loads X[row_base + (t>>3)][k0 + (t&7)*4 .. +4]
    long gr0 = row_base + (tid >> 3);
    long gr1 = gr0 + 64;
    if (gr0 >= N_NODES) gr0 = N_NODES - 1;   // clamp pad rows (discarded later)
    if (gr1 >= N_NODES) gr1 = N_NODES - 1;
    const float* gp0 = X + gr0 * F_IN + (tid & 7) * 4;
    const float* gp1 = X + gr1 * F_IN + (tid & 7) * 4;
    // wave-uniform LDS bases (HW adds lane*16)
    char* lds0 = (char*)As + wave * 1024;
    char* lds1 = (char*)As + 8192 + wave * 1024;

    const short* wtb = Wt + (wc * 64 + l15) * F_IN + quad * 8;
    const float* arow = As + (wr * 64 + l15) * 32 + quad * 8;

#pragma unroll 1
    for (int k0 = 0; k0 < F_IN; k0 += 32) {
        __syncthreads();
        load_lds16(gp0 + k0, lds0);
        load_lds16(gp1 + k0, lds1);
        __syncthreads();

        bf16x8 bfrag[4];
#pragma unroll
        for (int j = 0; j < 4; ++j)
            bfrag[j] = *(const bf16x8*)(wtb + j * 16 * F_IN + k0);

        bf16x8 afrag[4];
#pragma unroll
        for (int i = 0; i < 4; ++i) {
            const float* ap = arow + i * 16 * 32;
            f32x4 x0 = *(const f32x4*)ap;
            f32x4 x1 = *(const f32x4*)(ap + 4);
            u32x4 pv = { pack2(x0.x, x0.y), pack2(x0.z, x0.w),
                         pack2(x1.x, x1.y), pack2(x1.z, x1.w) };
            afrag[i] = __builtin_bit_cast(bf16x8, pv);
        }
#pragma unroll
        for (int i = 0; i < 4; ++i)
#pragma unroll
            for (int j = 0; j < 4; ++j)
                acc[i][j] = __builtin_amdgcn_mfma_f32_16x16x32_bf16(
                    afrag[i], bfrag[j], acc[i][j], 0, 0, 0);
    }

    // epilogue: C/D layout col=lane&15, row=quad*4+reg
#pragma unroll
    for (int i = 0; i < 4; ++i) {
#pragma unroll
        for (int rg = 0; rg < 4; ++rg) {
            long gm = row_base + wr * 64 + i * 16 + quad * 4 + rg;
            if (gm < N_NODES) {
#pragma unroll
                for (int j = 0; j < 4; ++j) {
                    int gn = wc * 64 + j * 16 + l15;
                    S[gm * F_OUT + gn] = f2b(acc[i][j][rg]);
                }
            }
        }
    }
}

// --- Kernel 2: out = spmm(adj, S). 2 rows per wave (one per half-wave),
// lane owns 8 cols (16B gather), depth-2 software pipeline.
__global__ __launch_bounds__(256) void k_spmm(const short* __restrict__ S,
                                              const int* __restrict__ ecol,
                                              const float* __restrict__ ev,
                                              const int* __restrict__ rp,
                                              float* __restrict__ out) {
    const int wave = threadIdx.x >> 6, lane = threadIdx.x & 63;
    const int half = lane >> 5, hl = lane & 31;
    const int r = (blockIdx.x * 4 + wave) * 2 + half;   // grid 12500 -> r < 100000
    const int lo = rp[r], hi = rp[r + 1];
    const short* sp = S + hl * 8;
    float a[8] = {0.f, 0.f, 0.f, 0.f, 0.f, 0.f, 0.f, 0.f};
    int e = lo;
    if (e < hi) {
        int c = ecol[e];
        float v = ev[e];
        bf16x8 s = *(const bf16x8*)(sp + (long)c * F_OUT);
        for (++e; e < hi; ++e) {
            int c2 = ecol[e];                        // next gather in flight
            float v2 = ev[e];                        // while current FMAs run
            bf16x8 s2 = *(const bf16x8*)(sp + (long)c2 * F_OUT);
#pragma unroll
            for (int i = 0; i < 8; ++i) a[i] += v * b2f(s[i]);
            v = v2; s = s2;
        }
#pragma unroll
        for (int i = 0; i < 8; ++i) a[i] += v * b2f(s[i]);
    }
    f32x4 o0 = {a[0], a[1], a[2], a[3]};
    f32x4 o1 = {a[4], a[5], a[6], a[7]};
    float* op = out + (long)r * F_OUT + hl * 8;
    *(f32x4*)op = o0;
    *(f32x4*)(op + 4) = o1;
}

extern "C" void kernel_launch(void* const* d_in, const int* in_sizes, int n_in,
                              void* d_out, int out_size, void* d_ws, size_t ws_size,
                              hipStream_t stream) {
    const float* x    = (const float*)d_in[0];
    const float* w    = (const float*)d_in[1];
    const int*   erow = (const int*)d_in[2];
    const int*   ecol = (const int*)d_in[3];
    const float* ev   = (const float*)d_in[4];
    float* out = (float*)d_out;

    // ws layout: [0,262144) Wt bf16 | [262144,662148) row_ptr | [1MiB,+51.2MB) S bf16
    char* ws = (char*)d_ws;
    short* Wt = (short*)ws;
    int*   rp = (int*)(ws + 262144);
    short* S  = (short*)(ws + (1 << 20));

    k_wconv<<<512, 256, 0, stream>>>(w, Wt);
    k_rowptr<<<(N_NODES + 256) / 256, 256, 0, stream>>>(erow, rp);
    k_gemm<<<(N_NODES + 127) / 128, 512, 0, stream>>>(x, Wt, S);
    k_spmm<<<N_NODES / 8, 256, 0, stream>>>(S, ecol, ev, rp, out);
}